// Round 1
// baseline (234.520 us; speedup 1.0000x reference)
//
#include <hip/hip_runtime.h>

using short8   = __attribute__((ext_vector_type(8))) short;
using f32x4    = __attribute__((ext_vector_type(4))) float;
using ushort4v = __attribute__((ext_vector_type(4))) unsigned short;

#define BN_EPS    1e-5f
#define ATT_SCALE 0.17677669529663687f   // 1/sqrt(32), folded into q projection

__device__ __forceinline__ unsigned short f2bf(float f) {
    union { float f; unsigned u; } v; v.f = f;
    return (unsigned short)((v.u + 0x7FFFu + ((v.u >> 16) & 1u)) >> 16);  // RNE
}

// ---------------------------------------------------------------------------
// Kernel 0: convert the stacked weight matrix [320 rows x 256] to bf16 and
// fold conv-bias + inference BN into per-row (scale, offset).
// Row layout: 0-31 = q_w, 32-63 = k_w, 64-319 = v_w.
// ---------------------------------------------------------------------------
__global__ void prep_kernel(
    const float* __restrict__ qw, const float* __restrict__ qb,
    const float* __restrict__ qg, const float* __restrict__ qbe,
    const float* __restrict__ qm, const float* __restrict__ qv,
    const float* __restrict__ kw, const float* __restrict__ kb,
    const float* __restrict__ kg, const float* __restrict__ kbe,
    const float* __restrict__ km, const float* __restrict__ kvv,
    const float* __restrict__ vw, const float* __restrict__ vb,
    const float* __restrict__ vg, const float* __restrict__ vbe,
    const float* __restrict__ vm, const float* __restrict__ vv,
    unsigned short* __restrict__ wq, float* __restrict__ scale,
    float* __restrict__ off)
{
    int r = blockIdx.x;      // 0..319
    int t = threadIdx.x;     // 0..63
    const float *wsrc, *g, *be, *mn, *vr, *bi;
    int rl;
    if (r < 32)      { rl = r;      wsrc = qw; g = qg; be = qbe; mn = qm; vr = qv;  bi = qb; }
    else if (r < 64) { rl = r - 32; wsrc = kw; g = kg; be = kbe; mn = km; vr = kvv; bi = kb; }
    else             { rl = r - 64; wsrc = vw; g = vg; be = vbe; mn = vm; vr = vv;  bi = vb; }

    float4 w4 = *(const float4*)(wsrc + rl * 256 + t * 4);
    ushort4v o;
    o.x = f2bf(w4.x); o.y = f2bf(w4.y); o.z = f2bf(w4.z); o.w = f2bf(w4.w);
    *(ushort4v*)(wq + r * 256 + t * 4) = o;

    if (t == 0) {
        float inv = g[rl] * rsqrtf(vr[rl] + BN_EPS);
        float ofv = bi[rl] * inv + be[rl] - mn[rl] * inv;   // (conv+b)*inv + (beta - mean*inv)
        float s = (r < 32) ? ATT_SCALE : 1.0f;              // fold 1/sqrt(dqk) into q rows
        scale[r] = inv * s;
        off[r]   = ofv * s;
    }
}

// ---------------------------------------------------------------------------
// Kernel 1: projections. Block = (batch, 64-col n-tile, rowgroup).
//   g=0: q (32 rows, reads x1) -> q_t[b][n][32] bf16
//   g=1: k (32 rows, reads x2) -> k_t[b][n][32] bf16
//   g=2..5: v (64 rows each, reads x2) -> v_bf[b][c][4096] bf16
// X tile [256 c][64 n] is transposed into LDS Xt[n][c] bf16 so both MFMA
// operands read 16B k-contiguous fragments.
// ---------------------------------------------------------------------------
#define XT_PITCH 264   // 256 + 8 pad -> 2-way (free) LDS bank aliasing on b128 reads

__global__ __launch_bounds__(256) void proj_kernel(
    const float* __restrict__ x1, const float* __restrict__ x2,
    const unsigned short* __restrict__ wq,
    const float* __restrict__ scale, const float* __restrict__ off,
    unsigned short* __restrict__ q_t, unsigned short* __restrict__ k_t,
    unsigned short* __restrict__ v_bf)
{
    __shared__ unsigned short Xt[64 * XT_PITCH];   // 33792 B
    int bx = blockIdx.x;
    int nt = bx & 63;
    int g  = (bx >> 6) % 6;
    int b  = bx / 384;
    int n0 = nt * 64;
    int tid = threadIdx.x;
    int wv = tid >> 6, lane = tid & 63;
    int m16 = lane & 15, qd = lane >> 4;

    const float* xb = ((g == 0) ? x1 : x2) + (size_t)b * 256 * 4096;

    // stage + transpose + bf16-convert the x tile (coalesced float4 reads)
    #pragma unroll
    for (int i = 0; i < 8; ++i) {
        int p  = i * 256 + tid;       // 0..2047
        int c2 = p >> 4;              // 0..127 (row pair)
        int u4 = (p & 15) * 4;        // 0..60  (n offset)
        float4 a = *(const float4*)(xb + (size_t)(2 * c2)     * 4096 + n0 + u4);
        float4 c = *(const float4*)(xb + (size_t)(2 * c2 + 1) * 4096 + n0 + u4);
        float av[4] = {a.x, a.y, a.z, a.w};
        float cv[4] = {c.x, c.y, c.z, c.w};
        #pragma unroll
        for (int u = 0; u < 4; ++u) {
            unsigned pk = (unsigned)f2bf(av[u]) | ((unsigned)f2bf(cv[u]) << 16);
            *(unsigned*)&Xt[(u4 + u) * XT_PITCH + 2 * c2] = pk;
        }
    }
    __syncthreads();

    int rb = (g == 0) ? 0 : (g == 1) ? 32 : 64 + (g - 2) * 64;
    f32x4 zero4 = {0.f, 0.f, 0.f, 0.f};

    if (g < 2) {
        // D[r][n] = W * X : A = W rows, B = Xt cols (wave owns n-subtile wv)
        f32x4 acc0 = zero4, acc1 = zero4;
        #pragma unroll
        for (int s = 0; s < 8; ++s) {
            short8 w0 = *(const short8*)(wq + (size_t)(rb +      m16) * 256 + s * 32 + qd * 8);
            short8 w1 = *(const short8*)(wq + (size_t)(rb + 16 + m16) * 256 + s * 32 + qd * 8);
            short8 xf = *(const short8*)&Xt[(16 * wv + m16) * XT_PITCH + s * 32 + qd * 8];
            acc0 = __builtin_amdgcn_mfma_f32_16x16x32_bf16(w0, xf, acc0, 0, 0, 0);
            acc1 = __builtin_amdgcn_mfma_f32_16x16x32_bf16(w1, xf, acc1, 0, 0, 0);
        }
        unsigned short* dst = (g == 0) ? q_t : k_t;
        int ncol = n0 + 16 * wv + m16;
        #pragma unroll
        for (int tm = 0; tm < 2; ++tm) {
            f32x4 acc = tm ? acc1 : acc0;
            int r0 = 16 * tm + 4 * qd;                 // local d base
            float4 sc = *(const float4*)(scale + rb + r0);
            float4 of = *(const float4*)(off   + rb + r0);
            ushort4v o;
            o.x = f2bf(acc.x * sc.x + of.x);
            o.y = f2bf(acc.y * sc.y + of.y);
            o.z = f2bf(acc.z * sc.z + of.z);
            o.w = f2bf(acc.w * sc.w + of.w);
            *(ushort4v*)(dst + ((size_t)b * 4096 + ncol) * 32 + r0) = o;
        }
    } else {
        // D[n][r] = X^T * W^T : A = Xt rows (n), B = W rows as cols (wave owns r-subtile wv)
        f32x4 acc[4] = {zero4, zero4, zero4, zero4};
        #pragma unroll
        for (int s = 0; s < 8; ++s) {
            short8 wf = *(const short8*)(wq + (size_t)(rb + 16 * wv + m16) * 256 + s * 32 + qd * 8);
            #pragma unroll
            for (int tm = 0; tm < 4; ++tm) {
                short8 xf = *(const short8*)&Xt[(16 * tm + m16) * XT_PITCH + s * 32 + qd * 8];
                acc[tm] = __builtin_amdgcn_mfma_f32_16x16x32_bf16(xf, wf, acc[tm], 0, 0, 0);
            }
        }
        int rglob = rb + 16 * wv + m16;
        int c = rglob - 64;                            // v channel 0..255
        float sc = scale[rglob], of = off[rglob];
        #pragma unroll
        for (int tm = 0; tm < 4; ++tm) {
            int nloc = 16 * tm + 4 * qd;
            ushort4v o;
            o.x = f2bf(acc[tm].x * sc + of);
            o.y = f2bf(acc[tm].y * sc + of);
            o.z = f2bf(acc[tm].z * sc + of);
            o.w = f2bf(acc[tm].w * sc + of);
            *(ushort4v*)(v_bf + ((size_t)b * 256 + c) * 4096 + n0 + nloc) = o;
        }
    }
}

// ---------------------------------------------------------------------------
// Kernel 2: fused flash attention (no-max online softmax; logits provably
// bounded ~|e|<10, exp fp32 safe). Block = (batch, 64-query tile), 8 waves.
// Wave w: QK strip (w&3, 16 queries) x key-half (w>>2); PV c-strip 32*w.
// P (exp of scores) round-trips through LDS with pitch 72 (2-way = free).
// K and V fragments load straight from global (L2-resident; b=bx&3 keeps one
// batch per XCD-pair L2).
// ---------------------------------------------------------------------------
#define P_PITCH 72

__global__ __launch_bounds__(512) void flash_kernel(
    const unsigned short* __restrict__ q_t, const unsigned short* __restrict__ k_t,
    const unsigned short* __restrict__ v_bf, float* __restrict__ out)
{
    __shared__ unsigned short P[64 * P_PITCH];   // 9216 B
    __shared__ float l_lds[64];

    int bx = blockIdx.x;
    int b  = bx & 3;           // XCD-affinity swizzle (perf-only)
    int mb = bx >> 2;          // 0..63 query tile
    int tid = threadIdx.x;
    int wv = tid >> 6, lane = tid & 63;
    int m16 = lane & 15, qd = lane >> 4;
    int strip = wv & 3, h = wv >> 2;

    if (tid < 64) l_lds[tid] = 0.0f;

    const unsigned short* ktb = k_t  + (size_t)b * 4096 * 32;
    const unsigned short* vbb = v_bf + (size_t)b * 256 * 4096;

    // Q A-fragment: held in registers for the whole kernel
    short8 Qf = *(const short8*)(q_t + ((size_t)b * 4096 + mb * 64 + 16 * strip + m16) * 32 + qd * 8);

    f32x4 zero4 = {0.f, 0.f, 0.f, 0.f};
    f32x4 acc[4][2];
    #pragma unroll
    for (int tm = 0; tm < 4; ++tm) { acc[tm][0] = zero4; acc[tm][1] = zero4; }
    float lp[4] = {0.f, 0.f, 0.f, 0.f};

    for (int kt = 0; kt < 64; ++kt) {
        int n0 = kt * 64;
        // QK^T for this wave's 16-query strip x 32-key half (d=32 = one K step)
        short8 K0 = *(const short8*)(ktb + (size_t)(n0 + 32 * h +      m16) * 32 + qd * 8);
        short8 K1 = *(const short8*)(ktb + (size_t)(n0 + 32 * h + 16 + m16) * 32 + qd * 8);
        f32x4 S0 = __builtin_amdgcn_mfma_f32_16x16x32_bf16(Qf, K0, zero4, 0, 0, 0);
        f32x4 S1 = __builtin_amdgcn_mfma_f32_16x16x32_bf16(Qf, K1, zero4, 0, 0, 0);
        float p0 = __expf(S0.x), p1 = __expf(S0.y), p2 = __expf(S0.z), p3 = __expf(S0.w);
        float p4 = __expf(S1.x), p5 = __expf(S1.y), p6 = __expf(S1.z), p7 = __expf(S1.w);
        lp[0] += p0 + p4; lp[1] += p1 + p5; lp[2] += p2 + p6; lp[3] += p3 + p7;

        __syncthreads();   // previous iteration's P readers are done
        {
            int row = 16 * strip + 4 * qd;
            int col = 32 * h + m16;
            P[(row + 0) * P_PITCH + col]      = f2bf(p0);
            P[(row + 1) * P_PITCH + col]      = f2bf(p1);
            P[(row + 2) * P_PITCH + col]      = f2bf(p2);
            P[(row + 3) * P_PITCH + col]      = f2bf(p3);
            P[(row + 0) * P_PITCH + col + 16] = f2bf(p4);
            P[(row + 1) * P_PITCH + col + 16] = f2bf(p5);
            P[(row + 2) * P_PITCH + col + 16] = f2bf(p6);
            P[(row + 3) * P_PITCH + col + 16] = f2bf(p7);
        }
        __syncthreads();   // P complete

        // O[m][c] += P[m][n] * V^T[n][c]; wave owns channels 32*wv..+32
        #pragma unroll
        for (int s = 0; s < 2; ++s) {
            short8 B0 = *(const short8*)(vbb + (size_t)(32 * wv +      m16) * 4096 + n0 + s * 32 + qd * 8);
            short8 B1 = *(const short8*)(vbb + (size_t)(32 * wv + 16 + m16) * 4096 + n0 + s * 32 + qd * 8);
            #pragma unroll
            for (int tm = 0; tm < 4; ++tm) {
                short8 A = *(const short8*)&P[(16 * tm + m16) * P_PITCH + s * 32 + qd * 8];
                acc[tm][0] = __builtin_amdgcn_mfma_f32_16x16x32_bf16(A, B0, acc[tm][0], 0, 0, 0);
                acc[tm][1] = __builtin_amdgcn_mfma_f32_16x16x32_bf16(A, B1, acc[tm][1], 0, 0, 0);
            }
        }
    }

    // finalize row sums: reduce over the 16 col-lanes, then combine waves via LDS
    #pragma unroll
    for (int r = 0; r < 4; ++r) {
        float v = lp[r];
        v += __shfl_xor(v, 1, 16);
        v += __shfl_xor(v, 2, 16);
        v += __shfl_xor(v, 4, 16);
        v += __shfl_xor(v, 8, 16);
        if (m16 == 0) atomicAdd(&l_lds[16 * strip + 4 * qd + r], v);
    }
    __syncthreads();
    if (tid < 64) l_lds[tid] = 1.0f / l_lds[tid];
    __syncthreads();

    float* ob = out + (size_t)b * 256 * 4096 + mb * 64;
    #pragma unroll
    for (int tm = 0; tm < 4; ++tm) {
        float4 inv = *(const float4*)&l_lds[16 * tm + 4 * qd];
        #pragma unroll
        for (int tc = 0; tc < 2; ++tc) {
            int c = 32 * wv + 16 * tc + m16;
            float4 o;
            o.x = acc[tm][tc].x * inv.x;
            o.y = acc[tm][tc].y * inv.y;
            o.z = acc[tm][tc].z * inv.z;
            o.w = acc[tm][tc].w * inv.w;
            *(float4*)(ob + (size_t)c * 4096 + 16 * tm + 4 * qd) = o;
        }
    }
}

// ---------------------------------------------------------------------------
// Workspace layout (bytes), total ~10.7 MB:
//   0        : wq    320*256 bf16  (163840)
//   163840   : scale 320 f32       (1280)
//   165120   : off   320 f32       (1280)
//   166400   : q_t   4*4096*32 bf16 (1 MiB)
//   +1 MiB   : k_t   (1 MiB)
//   +2 MiB   : v_bf  4*256*4096 bf16 (8 MiB)
// ---------------------------------------------------------------------------
extern "C" void kernel_launch(void* const* d_in, const int* in_sizes, int n_in,
                              void* d_out, int out_size, void* d_ws, size_t ws_size,
                              hipStream_t stream)
{
    const float* x1  = (const float*)d_in[0];
    const float* x2  = (const float*)d_in[1];
    const float* qw  = (const float*)d_in[2];
    const float* qb  = (const float*)d_in[3];
    const float* qg  = (const float*)d_in[4];
    const float* qbe = (const float*)d_in[5];
    const float* qm  = (const float*)d_in[6];
    const float* qv  = (const float*)d_in[7];
    const float* kw  = (const float*)d_in[8];
    const float* kb  = (const float*)d_in[9];
    const float* kg  = (const float*)d_in[10];
    const float* kbe = (const float*)d_in[11];
    const float* km  = (const float*)d_in[12];
    const float* kvv = (const float*)d_in[13];
    const float* vw  = (const float*)d_in[14];
    const float* vb  = (const float*)d_in[15];
    const float* vg  = (const float*)d_in[16];
    const float* vbe = (const float*)d_in[17];
    const float* vm  = (const float*)d_in[18];
    const float* vv  = (const float*)d_in[19];

    char* ws = (char*)d_ws;
    unsigned short* wq   = (unsigned short*)(ws + 0);
    float*          scale= (float*)(ws + 163840);
    float*          off  = (float*)(ws + 165120);
    unsigned short* q_t  = (unsigned short*)(ws + 166400);
    unsigned short* k_t  = (unsigned short*)(ws + 166400 + 1048576);
    unsigned short* v_bf = (unsigned short*)(ws + 166400 + 2097152);

    prep_kernel<<<320, 64, 0, stream>>>(qw, qb, qg, qbe, qm, qv,
                                        kw, kb, kg, kbe, km, kvv,
                                        vw, vb, vg, vbe, vm, vv,
                                        wq, scale, off);
    proj_kernel<<<1536, 256, 0, stream>>>(x1, x2, wq, scale, off, q_t, k_t, v_bf);
    flash_kernel<<<256, 512, 0, stream>>>(q_t, k_t, v_bf, (float*)d_out);
}